// Round 2
// baseline (490.288 us; speedup 1.0000x reference)
//
#include <hip/hip_runtime.h>

// ---------------- problem constants ----------------
#define N13E 16224      // 32*3*169
#define N26E 64896      // 32*3*676
#define N52E 259584     // 32*3*2704
#define NTOT 340704
#define BASE26 16224
#define BASE52 81120
#define KMAX 2048       // compaction capacity
#define TOPK 512

__device__ __forceinline__ float sigm(float x) { return 1.0f / (1.0f + expf(-x)); }

__device__ __forceinline__ unsigned long long pack_key(float v, int c) {
    unsigned u = __float_as_uint(v);
    unsigned ov = (u & 0x80000000u) ? ~u : (u | 0x80000000u);
    return (((unsigned long long)ov) << 32) | (unsigned long long)(unsigned)(127 - c);
}

// ================= K1: histogram + (last block) suffix-scan threshold =================
template <int HW>
__device__ __forceinline__ float load_logit(const float* __restrict__ p, int local) {
    int ba = local / HW;           // b*3 + a
    int hw = local - ba * HW;
    int b = ba / 3;
    int a = ba - b * 3;
    return p[(b * 255 + a * 85 + 4) * HW + hw];
}

__global__ void __launch_bounds__(256) k_hist_scan(const float* __restrict__ p13,
                                                   const float* __restrict__ p26,
                                                   const float* __restrict__ p52,
                                                   unsigned* __restrict__ hist,
                                                   unsigned* __restrict__ done,
                                                   unsigned* __restrict__ thr) {
    __shared__ unsigned tot[256];
    __shared__ unsigned amLast;
    int tid = threadIdx.x;
    int t = blockIdx.x * 256 + tid;
    if (t < NTOT) {
        float logit;
        if (t < N13E)               logit = load_logit<169>(p13, t);
        else if (t < N13E + N26E)   logit = load_logit<676>(p26, t - N13E);
        else                        logit = load_logit<2704>(p52, t - (N13E + N26E));
        float conf = sigm(logit);
        if (conf > 0.5f) {
            unsigned bin = (__float_as_uint(conf) >> 12) - 0x3F000u;
            bin = (bin > 2047u) ? 2047u : bin;
            atomicAdd(&hist[bin], 1u);
        }
    }
    __threadfence();              // release our hist updates
    __syncthreads();
    if (tid == 0) amLast = (atomicAdd(done, 1u) == gridDim.x - 1) ? 1u : 0u;
    __syncthreads();
    if (!amLast) return;
    __threadfence();              // acquire everyone's hist updates

    // ---- suffix scan over 2048 bins (256 threads x 8) ----
    unsigned loc[8]; unsigned s = 0u;
#pragma unroll
    for (int k = 0; k < 8; ++k) { loc[k] = hist[2047 - (tid * 8 + k)]; s += loc[k]; }
    tot[tid] = s;
    __syncthreads();
    for (int off = 1; off < 256; off <<= 1) {
        unsigned u = (tid >= off) ? tot[tid - off] : 0u;
        __syncthreads();
        tot[tid] += u;
        __syncthreads();
    }
    unsigned excl = tot[tid] - s;
    unsigned total = tot[255];
    if (total < (unsigned)TOPK) {
        if (tid == 0) *thr = 0x3F000001u;   // accept every conf > 0.5
    } else {
        unsigned run = excl;
#pragma unroll
        for (int k = 0; k < 8; ++k) {
            unsigned c = run + loc[k];
            if (run < (unsigned)TOPK && c >= (unsigned)TOPK) {
                int bin = 2047 - (tid * 8 + k);
                *thr = ((unsigned)(bin + 0x3F000)) << 12;
            }
            run = c;
        }
    }
}

// ================= K2: compact keys + (last block) O(n^2) rank sort =================
template <int HW, int BASE>
__device__ __forceinline__ void compact_one(const float* __restrict__ p, int local, unsigned thrv,
                                            unsigned* __restrict__ cnt,
                                            unsigned long long* __restrict__ keys) {
    int ba = local / HW;
    int hw = local - ba * HW;
    int b = ba / 3;
    int a = ba - b * 3;
    float logit = p[(b * 255 + a * 85 + 4) * HW + hw];
    float conf = sigm(logit);
    unsigned bits = __float_as_uint(conf);
    if (conf > 0.5f && bits >= thrv) {
        unsigned pos = atomicAdd(cnt, 1u);
        if (pos < (unsigned)KMAX) {
            unsigned concat = (unsigned)(BASE + (b * HW + hw) * 3 + a);
            keys[pos] = (((unsigned long long)bits) << 32) | (unsigned long long)(0xFFFFFFFFu - concat);
        }
    }
}

__global__ void __launch_bounds__(512) k_compact_rank(const float* __restrict__ p13,
                                                      const float* __restrict__ p26,
                                                      const float* __restrict__ p52,
                                                      const unsigned* __restrict__ thrp,
                                                      unsigned* __restrict__ cnt,
                                                      unsigned long long* __restrict__ keys,
                                                      unsigned* __restrict__ done,
                                                      unsigned long long* __restrict__ sorted) {
    __shared__ unsigned long long keysL[KMAX];    // 16 KB
    __shared__ unsigned long long sortedL[TOPK];  // 4 KB
    __shared__ unsigned amLast;
    int tid = threadIdx.x;
    int t = blockIdx.x * 512 + tid;
    if (t < NTOT) {
        unsigned thrv = *thrp;
        if (t < N13E)               compact_one<169, 0>(p13, t, thrv, cnt, keys);
        else if (t < N13E + N26E)   compact_one<676, BASE26>(p26, t - N13E, thrv, cnt, keys);
        else                        compact_one<2704, BASE52>(p52, t - (N13E + N26E), thrv, cnt, keys);
    }
    __threadfence();              // release our key writes
    __syncthreads();
    if (tid == 0) amLast = (atomicAdd(done, 1u) == gridDim.x - 1) ? 1u : 0u;
    __syncthreads();
    if (!amLast) return;
    __threadfence();              // acquire everyone's key writes

    unsigned n = *cnt; if (n > (unsigned)KMAX) n = (unsigned)KMAX;
    for (int j = tid; j < (int)n; j += 512) keysL[j] = keys[j];
    sortedL[tid] = 0ull;           // blockDim==512==TOPK
    __syncthreads();

    // each thread owns up to 4 keys; rank = #keys greater (keys unique)
    unsigned long long mine[4]; unsigned rk[4]; int nown = 0;
#pragma unroll
    for (int k = 0; k < 4; ++k) {
        int idx = tid + k * 512;
        if (idx < (int)n) { mine[nown] = keysL[idx]; rk[nown] = 0u; ++nown; }
    }
    for (int j = 0; j < (int)n; ++j) {
        unsigned long long kj = keysL[j];
        for (int m = 0; m < nown; ++m) rk[m] += (kj > mine[m]) ? 1u : 0u;
    }
    for (int m = 0; m < nown; ++m)
        if (rk[m] < (unsigned)TOPK) sortedL[rk[m]] = mine[m];
    __syncthreads();
    sorted[tid] = sortedL[tid];
}

// ================= K3: decode (8 lanes/box) + (last block) mask + NMS + output =================
template <int HW, int W>
__device__ __forceinline__ void decode8(const float* __restrict__ p, int local, float strideF,
                                        float aw0, float ah0, float aw1, float ah1, float aw2, float ah2,
                                        float conf, float* __restrict__ outrow, int l) {
    int a = local % 3;
    int cell = local / 3;
    int b = cell / HW;
    int hw = cell - b * HW;
    int h = hw / W;
    int wc = hw - h * W;
    int cb = b * 255 + a * 85;
    // 80-class argmax: lane l handles classes l, l+8, ..., l+72
    float v0 = p[(cb + 5 + l) * HW + hw];
    unsigned long long k1 = pack_key(v0, l);
#pragma unroll
    for (int k = 1; k < 10; ++k) {
        int c = l + 8 * k;
        float v = p[(cb + 5 + c) * HW + hw];
        unsigned long long kk = pack_key(v, c);
        if (kk > k1) k1 = kk;
    }
#pragma unroll
    for (int m = 4; m >= 1; m >>= 1) {
        unsigned long long o = __shfl_xor(k1, m, 64);
        if (o > k1) k1 = o;
    }
    if (l == 0) {
        int cls = 127 - (int)(unsigned)(k1 & 0xFFFFFFFFull);
        float t0 = p[(cb + 0) * HW + hw];
        float t1 = p[(cb + 1) * HW + hw];
        float t2 = p[(cb + 2) * HW + hw];
        float t3 = p[(cb + 3) * HW + hw];
        float aw = (a == 0) ? aw0 : ((a == 1) ? aw1 : aw2);
        float ah = (a == 0) ? ah0 : ((a == 1) ? ah1 : ah2);
        float sx = sigm(t0);
        float sy = sigm(t1);
        float bw = aw * expf(t2);
        float bh = ah * expf(t3);
        float cx = ((float)wc + sx) * strideF;
        float cy = ((float)h + sy) * strideF;
        float w0 = bw * 0.5f, h0 = bh * 0.5f;
        outrow[0] = conf;
        outrow[1] = cx - w0;
        outrow[2] = cy - h0;
        outrow[3] = cx + w0;
        outrow[4] = cy + h0;
        outrow[5] = (float)cls;
        outrow[6] = (float)b;
    }
}

__global__ void __launch_bounds__(512) k_decode_mask_nms(const float* __restrict__ p13,
                                                         const float* __restrict__ p26,
                                                         const float* __restrict__ p52,
                                                         const unsigned long long* __restrict__ sorted,
                                                         float* __restrict__ cand,
                                                         unsigned* __restrict__ done,
                                                         float* __restrict__ out) {
    __shared__ float cx1[TOPK], cy1[TOPK], cx2[TOPK], cy2[TOPK], car[TOPK], cco[TOPK];
    __shared__ unsigned long long smask[TOPK * 8];   // 32 KB
    __shared__ unsigned long long live[8], keepw[8];
    __shared__ unsigned amLast;
    int tid = threadIdx.x;

    // ---- decode phase: 64 boxes per block, 8 lanes per box ----
    int box = blockIdx.x * 64 + (tid >> 3);
    int l = tid & 7;
    unsigned long long key = sorted[box];
    unsigned sb = (unsigned)(key >> 32);
    float* row = cand + box * 7;
    if (sb == 0u) {
        if (l < 7) row[l] = 0.0f;
    } else {
        unsigned idx = 0xFFFFFFFFu - (unsigned)(key & 0xFFFFFFFFull);
        float conf = __uint_as_float(sb);
        if (idx < N13E)
            decode8<169, 13>(p13, (int)idx, 32.0f, 116.f, 90.f, 156.f, 198.f, 373.f, 326.f, conf, row, l);
        else if (idx < N13E + N26E)
            decode8<676, 26>(p26, (int)idx - BASE26, 16.0f, 30.f, 61.f, 62.f, 45.f, 59.f, 119.f, conf, row, l);
        else
            decode8<2704, 52>(p52, (int)idx - BASE52, 8.0f, 10.f, 13.f, 16.f, 30.f, 33.f, 23.f, conf, row, l);
    }
    __threadfence();              // release our cand rows
    __syncthreads();
    if (tid == 0) amLast = (atomicAdd(done, 1u) == gridDim.x - 1) ? 1u : 0u;
    __syncthreads();
    if (!amLast) return;
    __threadfence();              // acquire all cand rows

    // ---- stage cand into LDS ----
    {
        int p = tid;              // 512 threads, 512 boxes
        float c0 = cand[p * 7 + 0];
        float x1 = cand[p * 7 + 1], y1 = cand[p * 7 + 2];
        float x2 = cand[p * 7 + 3], y2 = cand[p * 7 + 4];
        cco[p] = c0; cx1[p] = x1; cy1[p] = y1; cx2[p] = x2; cy2[p] = y2;
        car[p] = fmaxf(x2 - x1, 0.f) * fmaxf(y2 - y1, 0.f);
    }
    __syncthreads();

    // ---- mask phase: thread i owns suppression row i (8 words) ----
    {
        int i = tid;
        float x1 = cx1[i], y1 = cy1[i], x2 = cx2[i], y2 = cy2[i];
        float ai = car[i];
#pragma unroll
        for (int jw = 0; jw < 8; ++jw) {
            unsigned long long m = 0ull;
            int j0 = jw * 64;
            if (i < j0 + 63) {    // word has at least one j > i
                for (int bj = 0; bj < 64; ++bj) {
                    int j = j0 + bj;
                    float jx1 = cx1[j], jy1 = cy1[j], jx2 = cx2[j], jy2 = cy2[j];
                    float aj = car[j];
                    float xx1 = fmaxf(x1, jx1), yy1 = fmaxf(y1, jy1);
                    float xx2 = fminf(x2, jx2), yy2 = fminf(y2, jy2);
                    float inter = fmaxf(xx2 - xx1, 0.f) * fmaxf(yy2 - yy1, 0.f);
                    float iou = inter / (((ai + aj) - inter) + 1e-9f);
                    if ((j > i) && (iou > 0.3f)) m |= (1ull << bj);
                }
            }
            smask[i * 8 + jw] = m;
        }
    }
    // ---- validity ballot ----
    bool validt = cco[tid] > 0.5f;
    unsigned long long bal = __ballot(validt);
    if ((tid & 63) == 0) live[tid >> 6] = bal;
    __syncthreads();

    // ---- serial greedy sweep on 64 lanes ----
    if (tid < 64) {
        int lane = tid;
        int lw = lane & 7;                       // word this lane owns
        unsigned long long r = 0ull;             // removed bits for word lw
#pragma unroll
        for (int w = 0; w < 8; ++w) {
            unsigned long long lvw = live[w];
#pragma unroll 8
            for (int b2 = 0; b2 < 64; ++b2) {
                int i = w * 64 + b2;
                unsigned long long rowv = smask[i * 8 + lw];
                unsigned rlo = (unsigned)__builtin_amdgcn_readlane((int)(unsigned)(r & 0xFFFFFFFFull), w);
                unsigned rhi = (unsigned)__builtin_amdgcn_readlane((int)(unsigned)(r >> 32), w);
                unsigned long long rw = (((unsigned long long)rhi) << 32) | (unsigned long long)rlo;
                bool acc = (((lvw >> b2) & 1ull) != 0ull) && (((rw >> b2) & 1ull) == 0ull);
                if (acc) r |= rowv;
            }
        }
        if (lane < 8) keepw[lane] = live[lane] & ~r;
    }
    __syncthreads();

    // ---- masked output ----
    for (int p = tid; p < TOPK * 7; p += 512) {
        int i = p / 7;
        unsigned long long kb = (keepw[i >> 6] >> (i & 63)) & 1ull;
        out[p] = kb ? cand[p] : 0.0f;
    }
}

// ---------------- launch ----------------
extern "C" void kernel_launch(void* const* d_in, const int* in_sizes, int n_in,
                              void* d_out, int out_size, void* d_ws, size_t ws_size,
                              hipStream_t stream) {
    const float* p13 = (const float*)d_in[0];
    const float* p26 = (const float*)d_in[1];
    const float* p52 = (const float*)d_in[2];
    float* out = (float*)d_out;
    char* ws = (char*)d_ws;

    unsigned* hist             = (unsigned*)(ws + 0);          // 2048 u32
    unsigned* cnt              = (unsigned*)(ws + 8192);       // 1 u32
    unsigned* done1            = (unsigned*)(ws + 8196);
    unsigned* done2            = (unsigned*)(ws + 8200);
    unsigned* done3            = (unsigned*)(ws + 8204);
    unsigned* thr              = (unsigned*)(ws + 8208);
    unsigned long long* keys   = (unsigned long long*)(ws + 8704);   // 2048 u64
    unsigned long long* sorted = (unsigned long long*)(ws + 25088);  // 512 u64
    float* cand                = (float*)(ws + 29184);               // 512*7 f32

    // zero hist + cnt + done counters
    hipMemsetAsync(ws, 0, 8208, stream);

    int gh = (NTOT + 255) / 256;   // 1331
    int gc = (NTOT + 511) / 512;   // 666
    k_hist_scan<<<gh, 256, 0, stream>>>(p13, p26, p52, hist, done1, thr);
    k_compact_rank<<<gc, 512, 0, stream>>>(p13, p26, p52, thr, cnt, keys, done2, sorted);
    k_decode_mask_nms<<<8, 512, 0, stream>>>(p13, p26, p52, sorted, cand, done3, out);
}

// Round 3
// 368.718 us; speedup vs baseline: 1.3297x; 1.3297x over previous
//
#include <hip/hip_runtime.h>

// ---------------- problem constants ----------------
#define N13E 16224      // 32*3*169
#define N26E 64896      // 32*3*676
#define N52E 259584     // 32*3*2704
#define NTOT 340704
#define BASE26 16224
#define BASE52 81120
#define KMAX 2048       // compaction capacity
#define TOPK 512

__device__ __forceinline__ float sigm(float x) { return 1.0f / (1.0f + expf(-x)); }

__device__ __forceinline__ unsigned long long pack_key(float v, int c) {
    unsigned u = __float_as_uint(v);
    unsigned ov = (u & 0x80000000u) ? ~u : (u | 0x80000000u);
    return (((unsigned long long)ov) << 32) | (unsigned long long)(unsigned)(127 - c);
}

// ================= K1: histogram of conf bits =================
template <int HW>
__device__ __forceinline__ float load_logit(const float* __restrict__ p, int local) {
    int ba = local / HW;           // b*3 + a
    int hw = local - ba * HW;
    int b = ba / 3;
    int a = ba - b * 3;
    return p[(b * 255 + a * 85 + 4) * HW + hw];
}

__global__ void __launch_bounds__(256) k_hist(const float* __restrict__ p13,
                                              const float* __restrict__ p26,
                                              const float* __restrict__ p52,
                                              unsigned* __restrict__ hist) {
    int t = blockIdx.x * 256 + threadIdx.x;
    if (t >= NTOT) return;
    float logit;
    if (t < N13E)               logit = load_logit<169>(p13, t);
    else if (t < N13E + N26E)   logit = load_logit<676>(p26, t - N13E);
    else                        logit = load_logit<2704>(p52, t - (N13E + N26E));
    float conf = sigm(logit);
    if (conf > 0.5f) {
        unsigned bin = (__float_as_uint(conf) >> 12) - 0x3F000u;
        bin = (bin > 2047u) ? 2047u : bin;
        atomicAdd(&hist[bin], 1u);
    }
}

// ================= K2: per-block threshold scan (redundant, L2-hot) + compact =================
template <int HW, int BASE>
__device__ __forceinline__ void compact_one(const float* __restrict__ p, int local, unsigned thrv,
                                            unsigned* __restrict__ cnt,
                                            unsigned long long* __restrict__ keys) {
    int ba = local / HW;
    int hw = local - ba * HW;
    int b = ba / 3;
    int a = ba - b * 3;
    float logit = p[(b * 255 + a * 85 + 4) * HW + hw];
    float conf = sigm(logit);
    unsigned bits = __float_as_uint(conf);
    if (conf > 0.5f && bits >= thrv) {
        unsigned pos = atomicAdd(cnt, 1u);
        if (pos < (unsigned)KMAX) {
            unsigned concat = (unsigned)(BASE + (b * HW + hw) * 3 + a);
            keys[pos] = (((unsigned long long)bits) << 32) | (unsigned long long)(0xFFFFFFFFu - concat);
        }
    }
}

__global__ void __launch_bounds__(512) k_compact_scan(const float* __restrict__ p13,
                                                      const float* __restrict__ p26,
                                                      const float* __restrict__ p52,
                                                      const unsigned* __restrict__ hist,
                                                      unsigned* __restrict__ cnt,
                                                      unsigned long long* __restrict__ keys) {
    __shared__ unsigned tot[512];
    __shared__ unsigned thrS;
    int tid = threadIdx.x;

    // ---- threshold scan: 512 threads x 4 bins, suffix sums from the top ----
    unsigned loc[4]; unsigned s = 0u;
#pragma unroll
    for (int k = 0; k < 4; ++k) { loc[k] = hist[2047 - (tid * 4 + k)]; s += loc[k]; }
    tot[tid] = s;
    __syncthreads();
    for (int off = 1; off < 512; off <<= 1) {
        unsigned u = (tid >= off) ? tot[tid - off] : 0u;
        __syncthreads();
        tot[tid] += u;
        __syncthreads();
    }
    unsigned excl = tot[tid] - s;
    unsigned total = tot[511];
    if (total < (unsigned)TOPK) {
        if (tid == 0) thrS = 0x3F000001u;     // accept every conf > 0.5 (n = total < 512)
    } else {
        unsigned run = excl;
#pragma unroll
        for (int k = 0; k < 4; ++k) {
            unsigned c = run + loc[k];
            if (run < (unsigned)TOPK && c >= (unsigned)TOPK) {  // unique crossing
                int bin = 2047 - (tid * 4 + k);
                thrS = ((unsigned)(bin + 0x3F000)) << 12;
            }
            run = c;
        }
    }
    __syncthreads();
    unsigned thrv = thrS;

    // ---- compact ----
    int t = blockIdx.x * 512 + tid;
    if (t >= NTOT) return;
    if (t < N13E)               compact_one<169, 0>(p13, t, thrv, cnt, keys);
    else if (t < N13E + N26E)   compact_one<676, BASE26>(p26, t - N13E, thrv, cnt, keys);
    else                        compact_one<2704, BASE52>(p52, t - (N13E + N26E), thrv, cnt, keys);
}

// ================= K3: per-block rank-select (redundant) + decode =================
template <int HW, int W>
__device__ __forceinline__ void decode8(const float* __restrict__ p, int local, float strideF,
                                        float aw0, float ah0, float aw1, float ah1, float aw2, float ah2,
                                        float conf, float* __restrict__ outrow, int l) {
    int a = local % 3;
    int cell = local / 3;
    int b = cell / HW;
    int hw = cell - b * HW;
    int h = hw / W;
    int wc = hw - h * W;
    int cb = b * 255 + a * 85;
    // 80-class argmax: lane l handles classes l, l+8, ..., l+72
    float v0 = p[(cb + 5 + l) * HW + hw];
    unsigned long long k1 = pack_key(v0, l);
#pragma unroll
    for (int k = 1; k < 10; ++k) {
        int c = l + 8 * k;
        float v = p[(cb + 5 + c) * HW + hw];
        unsigned long long kk = pack_key(v, c);
        if (kk > k1) k1 = kk;
    }
#pragma unroll
    for (int m = 4; m >= 1; m >>= 1) {          // xor masks 4,2,1 stay inside the 8-lane group
        unsigned long long o = __shfl_xor(k1, m, 64);
        if (o > k1) k1 = o;
    }
    if (l == 0) {
        int cls = 127 - (int)(unsigned)(k1 & 0xFFFFFFFFull);
        float t0 = p[(cb + 0) * HW + hw];
        float t1 = p[(cb + 1) * HW + hw];
        float t2 = p[(cb + 2) * HW + hw];
        float t3 = p[(cb + 3) * HW + hw];
        float aw = (a == 0) ? aw0 : ((a == 1) ? aw1 : aw2);
        float ah = (a == 0) ? ah0 : ((a == 1) ? ah1 : ah2);
        float sx = sigm(t0);
        float sy = sigm(t1);
        float bw = aw * expf(t2);
        float bh = ah * expf(t3);
        float cx = ((float)wc + sx) * strideF;
        float cy = ((float)h + sy) * strideF;
        float w0 = bw * 0.5f, h0 = bh * 0.5f;
        outrow[0] = conf;
        outrow[1] = cx - w0;
        outrow[2] = cy - h0;
        outrow[3] = cx + w0;
        outrow[4] = cy + h0;
        outrow[5] = (float)cls;
        outrow[6] = (float)b;
    }
}

__global__ void __launch_bounds__(512) k_decode_rank(const float* __restrict__ p13,
                                                     const float* __restrict__ p26,
                                                     const float* __restrict__ p52,
                                                     const unsigned* __restrict__ cnt,
                                                     const unsigned long long* __restrict__ keys,
                                                     float* __restrict__ cand) {
    __shared__ unsigned long long keysL[KMAX];     // 16 KB
    __shared__ unsigned long long sortedL[64];     // this block's 64 boxes
    int tid = threadIdx.x;
    int lo = blockIdx.x * 64;                      // rank range [lo, lo+64)

    unsigned n = *cnt; if (n > (unsigned)KMAX) n = (unsigned)KMAX;
    for (int j = tid; j < (int)n; j += 512) keysL[j] = keys[j];
    if (tid < 64) sortedL[tid] = 0ull;
    __syncthreads();

    // each thread owns up to 4 keys; rank = #keys greater (keys unique)
    unsigned long long mine[4]; unsigned rk[4]; int nown = 0;
#pragma unroll
    for (int k = 0; k < 4; ++k) {
        int idx = tid + k * 512;
        if (idx < (int)n) { mine[nown] = keysL[idx]; rk[nown] = 0u; ++nown; }
    }
    for (int j = 0; j < (int)n; ++j) {
        unsigned long long kj = keysL[j];
        for (int m = 0; m < nown; ++m) rk[m] += (kj > mine[m]) ? 1u : 0u;
    }
    for (int m = 0; m < nown; ++m) {
        int r = (int)rk[m];
        if (r >= lo && r < lo + 64) sortedL[r - lo] = mine[m];
    }
    __syncthreads();

    // ---- decode: 8 lanes per box, 64 boxes per block ----
    int bb = tid >> 3;
    int l = tid & 7;
    int box = lo + bb;
    unsigned long long key = sortedL[bb];
    unsigned sb = (unsigned)(key >> 32);
    float* row = cand + box * 7;
    if (sb == 0u) {
        if (l < 7) row[l] = 0.0f;
        return;
    }
    unsigned idx = 0xFFFFFFFFu - (unsigned)(key & 0xFFFFFFFFull);
    float conf = __uint_as_float(sb);
    if (idx < N13E)
        decode8<169, 13>(p13, (int)idx, 32.0f, 116.f, 90.f, 156.f, 198.f, 373.f, 326.f, conf, row, l);
    else if (idx < N13E + N26E)
        decode8<676, 26>(p26, (int)idx - BASE26, 16.0f, 30.f, 61.f, 62.f, 45.f, 59.f, 119.f, conf, row, l);
    else
        decode8<2704, 52>(p52, (int)idx - BASE52, 8.0f, 10.f, 13.f, 16.f, 30.f, 33.f, 23.f, conf, row, l);
}

// ================= K4: mask + serial greedy NMS + masked output (1 block) =================
__global__ void __launch_bounds__(512) k_nms(const float* __restrict__ cand,
                                             float* __restrict__ out) {
    __shared__ float cx1[TOPK], cy1[TOPK], cx2[TOPK], cy2[TOPK], car[TOPK], cco[TOPK];
    __shared__ unsigned long long smask[TOPK * 8];   // 32 KB
    __shared__ unsigned long long live[8], keepw[8];
    int tid = threadIdx.x;

    // ---- stage cand into LDS ----
    {
        int p = tid;              // 512 threads, 512 boxes
        float c0 = cand[p * 7 + 0];
        float x1 = cand[p * 7 + 1], y1 = cand[p * 7 + 2];
        float x2 = cand[p * 7 + 3], y2 = cand[p * 7 + 4];
        cco[p] = c0; cx1[p] = x1; cy1[p] = y1; cx2[p] = x2; cy2[p] = y2;
        car[p] = fmaxf(x2 - x1, 0.f) * fmaxf(y2 - y1, 0.f);
    }
    __syncthreads();

    // ---- mask: thread i owns suppression row i (8 words), triangle-skipped ----
    {
        int i = tid;
        float x1 = cx1[i], y1 = cy1[i], x2 = cx2[i], y2 = cy2[i];
        float ai = car[i];
#pragma unroll
        for (int jw = 0; jw < 8; ++jw) {
            unsigned long long m = 0ull;
            int j0 = jw * 64;
            if (i < j0 + 63) {    // word has at least one j > i
                for (int bj = 0; bj < 64; ++bj) {
                    int j = j0 + bj;
                    float jx1 = cx1[j], jy1 = cy1[j], jx2 = cx2[j], jy2 = cy2[j];
                    float aj = car[j];
                    float xx1 = fmaxf(x1, jx1), yy1 = fmaxf(y1, jy1);
                    float xx2 = fminf(x2, jx2), yy2 = fminf(y2, jy2);
                    float inter = fmaxf(xx2 - xx1, 0.f) * fmaxf(yy2 - yy1, 0.f);
                    float iou = inter / (((ai + aj) - inter) + 1e-9f);
                    if ((j > i) && (iou > 0.3f)) m |= (1ull << bj);
                }
            }
            smask[i * 8 + jw] = m;
        }
    }
    // ---- validity ballot ----
    bool validt = cco[tid] > 0.5f;
    unsigned long long bal = __ballot(validt);
    if ((tid & 63) == 0) live[tid >> 6] = bal;
    __syncthreads();

    // ---- serial greedy sweep on 64 lanes ----
    if (tid < 64) {
        int lane = tid;
        int lw = lane & 7;                       // word this lane owns
        unsigned long long r = 0ull;             // removed bits for word lw
#pragma unroll
        for (int w = 0; w < 8; ++w) {
            unsigned long long lvw = live[w];
#pragma unroll 8
            for (int b2 = 0; b2 < 64; ++b2) {
                int i = w * 64 + b2;
                unsigned long long rowv = smask[i * 8 + lw];
                unsigned rlo = (unsigned)__builtin_amdgcn_readlane((int)(unsigned)(r & 0xFFFFFFFFull), w);
                unsigned rhi = (unsigned)__builtin_amdgcn_readlane((int)(unsigned)(r >> 32), w);
                unsigned long long rw = (((unsigned long long)rhi) << 32) | (unsigned long long)rlo;
                bool acc = (((lvw >> b2) & 1ull) != 0ull) && (((rw >> b2) & 1ull) == 0ull);
                if (acc) r |= rowv;
            }
        }
        if (lane < 8) keepw[lane] = live[lane] & ~r;
    }
    __syncthreads();

    // ---- masked output ----
    for (int p = tid; p < TOPK * 7; p += 512) {
        int i = p / 7;
        unsigned long long kb = (keepw[i >> 6] >> (i & 63)) & 1ull;
        out[p] = kb ? cand[p] : 0.0f;
    }
}

// ---------------- launch ----------------
extern "C" void kernel_launch(void* const* d_in, const int* in_sizes, int n_in,
                              void* d_out, int out_size, void* d_ws, size_t ws_size,
                              hipStream_t stream) {
    const float* p13 = (const float*)d_in[0];
    const float* p26 = (const float*)d_in[1];
    const float* p52 = (const float*)d_in[2];
    float* out = (float*)d_out;
    char* ws = (char*)d_ws;

    unsigned* hist           = (unsigned*)(ws + 0);                // 2048 u32
    unsigned* cnt            = (unsigned*)(ws + 8192);             // 1 u32
    unsigned long long* keys = (unsigned long long*)(ws + 8704);   // 2048 u64
    float* cand              = (float*)(ws + 25088);               // 512*7 f32

    hipMemsetAsync(ws, 0, 8196, stream);   // zero hist + cnt

    int gh = (NTOT + 255) / 256;   // 1331
    int gc = (NTOT + 511) / 512;   // 666
    k_hist<<<gh, 256, 0, stream>>>(p13, p26, p52, hist);
    k_compact_scan<<<gc, 512, 0, stream>>>(p13, p26, p52, hist, cnt, keys);
    k_decode_rank<<<8, 512, 0, stream>>>(p13, p26, p52, cnt, keys, cand);
    k_nms<<<1, 512, 0, stream>>>(cand, out);
}

// Round 4
// 325.880 us; speedup vs baseline: 1.5045x; 1.1315x over previous
//
#include <hip/hip_runtime.h>
#include <hip/hip_cooperative_groups.h>

namespace cg = cooperative_groups;

// ---------------- problem constants ----------------
#define N13E 16224      // 32*3*169
#define N26E 64896      // 32*3*676
#define NTOT 340704
#define BASE26 16224
#define BASE52 81120
#define KMAX 2048
#define TOPK 512
#define GRID 256
#define BLK 512
#define NTH (GRID * BLK)   // 131072

__device__ __forceinline__ float sigm(float x) { return 1.0f / (1.0f + expf(-x)); }

__device__ __forceinline__ unsigned long long pack_key(float v, int c) {
    unsigned u = __float_as_uint(v);
    unsigned ov = (u & 0x80000000u) ? ~u : (u | 0x80000000u);
    return (((unsigned long long)ov) << 32) | (unsigned long long)(unsigned)(127 - c);
}

template <int HW>
__device__ __forceinline__ float load_logit(const float* __restrict__ p, int local) {
    int ba = local / HW;           // b*3 + a
    int hw = local - ba * HW;
    int b = ba / 3;
    int a = ba - b * 3;
    return p[(b * 255 + a * 85 + 4) * HW + hw];
}

template <int HW, int BASE>
__device__ __forceinline__ unsigned concat_of(int local) {
    int ba = local / HW;
    int hw = local - ba * HW;
    int b = ba / 3;
    int a = ba - b * 3;
    return (unsigned)(BASE + (b * HW + hw) * 3 + a);
}

// 64-lane decode (R1-validated)
template <int HW, int W>
__device__ __forceinline__ void decode64(const float* __restrict__ p, int local, float strideF,
                                         float aw0, float ah0, float aw1, float ah1, float aw2, float ah2,
                                         float conf, float* __restrict__ outrow, int lane) {
    int a = local % 3;
    int cell = local / 3;
    int b = cell / HW;
    int hw = cell - b * HW;
    int h = hw / W;
    int wc = hw - h * W;
    int cb = b * 255 + a * 85;
    float v1 = p[(cb + 5 + lane) * HW + hw];
    unsigned long long k1 = pack_key(v1, lane);
    if (lane < 16) {
        float v2 = p[(cb + 69 + lane) * HW + hw];   // classes 64..79
        unsigned long long k2 = pack_key(v2, lane + 64);
        if (k2 > k1) k1 = k2;
    }
#pragma unroll
    for (int m = 32; m >= 1; m >>= 1) {
        unsigned long long o = __shfl_xor(k1, m, 64);
        if (o > k1) k1 = o;
    }
    if (lane == 0) {
        int cls = 127 - (int)(unsigned)(k1 & 0xFFFFFFFFull);
        float t0 = p[(cb + 0) * HW + hw];
        float t1 = p[(cb + 1) * HW + hw];
        float t2 = p[(cb + 2) * HW + hw];
        float t3 = p[(cb + 3) * HW + hw];
        float aw = (a == 0) ? aw0 : ((a == 1) ? aw1 : aw2);
        float ah = (a == 0) ? ah0 : ((a == 1) ? ah1 : ah2);
        float sx = sigm(t0);
        float sy = sigm(t1);
        float bw = aw * expf(t2);
        float bh = ah * expf(t3);
        float cx = ((float)wc + sx) * strideF;
        float cy = ((float)h + sy) * strideF;
        float w0 = bw * 0.5f, h0 = bh * 0.5f;
        outrow[0] = conf;
        outrow[1] = cx - w0;
        outrow[2] = cy - h0;
        outrow[3] = cx + w0;
        outrow[4] = cy + h0;
        outrow[5] = (float)cls;
        outrow[6] = (float)b;
    }
}

__global__ void __launch_bounds__(BLK) k_all(const float* __restrict__ p13,
                                             const float* __restrict__ p26,
                                             const float* __restrict__ p52,
                                             unsigned* __restrict__ hist,
                                             unsigned* __restrict__ cnt,
                                             unsigned long long* __restrict__ keys,
                                             float* __restrict__ cand,
                                             unsigned long long* __restrict__ smaskG,
                                             float* __restrict__ out) {
    cg::grid_group gg = cg::this_grid();
    __shared__ unsigned tot[BLK];
    __shared__ unsigned thrS;
    __shared__ unsigned long long keysL[KMAX];      // 16 KB
    __shared__ unsigned long long sortedL[8];
    __shared__ float sx1[TOPK], sy1[TOPK], sx2[TOPK], sy2[TOPK];  // 8 KB
    __shared__ unsigned long long smask[TOPK * 8];  // 32 KB
    __shared__ unsigned long long live[8], keepw[8];

    int tid = threadIdx.x;
    int gtid = blockIdx.x * BLK + tid;

    // ======== P1: sigmoid + histogram (confs cached in VGPRs) ========
    float confr[3];
#pragma unroll
    for (int k = 0; k < 3; ++k) {
        int t = gtid + k * NTH;
        confr[k] = 0.0f;
        if (t < NTOT) {
            float logit;
            if (t < N13E)             logit = load_logit<169>(p13, t);
            else if (t < N13E + N26E) logit = load_logit<676>(p26, t - N13E);
            else                      logit = load_logit<2704>(p52, t - (N13E + N26E));
            float conf = sigm(logit);
            confr[k] = conf;
            if (conf > 0.5f) {
                unsigned bin = (__float_as_uint(conf) >> 12) - 0x3F000u;
                bin = (bin > 2047u) ? 2047u : bin;
                atomicAdd(&hist[bin], 1u);
            }
        }
    }
    gg.sync();

    // ======== P2: per-block threshold scan + compact from registers ========
    {
        unsigned loc[4]; unsigned s = 0u;
#pragma unroll
        for (int k = 0; k < 4; ++k) { loc[k] = hist[2047 - (tid * 4 + k)]; s += loc[k]; }
        tot[tid] = s;
        __syncthreads();
        for (int off = 1; off < BLK; off <<= 1) {
            unsigned u = (tid >= off) ? tot[tid - off] : 0u;
            __syncthreads();
            tot[tid] += u;
            __syncthreads();
        }
        unsigned excl = tot[tid] - s;
        unsigned total = tot[BLK - 1];
        if (total < (unsigned)TOPK) {
            if (tid == 0) thrS = 0x3F000001u;     // accept every conf > 0.5
        } else {
            unsigned run = excl;
#pragma unroll
            for (int k = 0; k < 4; ++k) {
                unsigned c = run + loc[k];
                if (run < (unsigned)TOPK && c >= (unsigned)TOPK) {  // unique crossing
                    int bin = 2047 - (tid * 4 + k);
                    thrS = ((unsigned)(bin + 0x3F000)) << 12;
                }
                run = c;
            }
        }
    }
    __syncthreads();
    {
        unsigned thrv = thrS;
#pragma unroll
        for (int k = 0; k < 3; ++k) {
            int t = gtid + k * NTH;
            if (t < NTOT) {
                float conf = confr[k];
                unsigned bits = __float_as_uint(conf);
                if (conf > 0.5f && bits >= thrv) {
                    unsigned pos = atomicAdd(cnt, 1u);
                    if (pos < (unsigned)KMAX) {
                        unsigned concat;
                        if (t < N13E)             concat = concat_of<169, 0>(t);
                        else if (t < N13E + N26E) concat = concat_of<676, BASE26>(t - N13E);
                        else                      concat = concat_of<2704, BASE52>(t - (N13E + N26E));
                        keys[pos] = (((unsigned long long)bits) << 32) |
                                    (unsigned long long)(0xFFFFFFFFu - concat);
                    }
                }
            }
        }
    }
    gg.sync();

    // ======== P3: rank-select (blocks 0..63, unrolled) + decode 8 boxes/block ========
    if (blockIdx.x < 64) {
        unsigned n = *cnt; if (n > (unsigned)KMAX) n = (unsigned)KMAX;
        int npad = ((int)n + 7) & ~7;
        for (int j = tid; j < npad; j += BLK) keysL[j] = (j < (int)n) ? keys[j] : 0ull;
        if (tid < 8) sortedL[tid] = 0ull;
        __syncthreads();
        int lo = blockIdx.x * 8;
        unsigned long long mine[4]; unsigned rk[4]; int nown = 0;
#pragma unroll
        for (int k = 0; k < 4; ++k) {
            int idx = tid + k * BLK;
            if (idx < (int)n) { mine[nown] = keysL[idx]; rk[nown] = 0u; ++nown; }
        }
        for (int j = 0; j < npad; j += 8) {
            unsigned long long kk[8];
#pragma unroll
            for (int u = 0; u < 8; ++u) kk[u] = keysL[j + u];
            for (int m = 0; m < nown; ++m) {
                unsigned acc = 0u;
#pragma unroll
                for (int u = 0; u < 8; ++u) acc += (kk[u] > mine[m]) ? 1u : 0u;
                rk[m] += acc;
            }
        }
        for (int m = 0; m < nown; ++m) {
            unsigned r = rk[m];
            if (r >= (unsigned)lo && r < (unsigned)(lo + 8)) sortedL[r - lo] = mine[m];
        }
        __syncthreads();

        int bb = tid >> 6;
        int lane = tid & 63;
        int box = lo + bb;
        unsigned long long key = sortedL[bb];
        unsigned sb = (unsigned)(key >> 32);
        float* row = cand + box * 7;
        if (sb == 0u) {
            if (lane < 7) row[lane] = 0.0f;
        } else {
            unsigned idx = 0xFFFFFFFFu - (unsigned)(key & 0xFFFFFFFFull);
            float conf = __uint_as_float(sb);
            if (idx < N13E)
                decode64<169, 13>(p13, (int)idx, 32.0f, 116.f, 90.f, 156.f, 198.f, 373.f, 326.f, conf, row, lane);
            else if (idx < N13E + N26E)
                decode64<676, 26>(p26, (int)idx - BASE26, 16.0f, 30.f, 61.f, 62.f, 45.f, 59.f, 119.f, conf, row, lane);
            else
                decode64<2704, 52>(p52, (int)idx - BASE52, 8.0f, 10.f, 13.f, 16.f, 30.f, 33.f, 23.f, conf, row, lane);
        }
    }
    gg.sync();

    // ======== P4: suppression mask, one wave per 64-bit word ========
    for (int p = tid; p < TOPK; p += BLK) {
        const float* r = cand + p * 7;
        sx1[p] = r[1]; sy1[p] = r[2]; sx2[p] = r[3]; sy2[p] = r[4];
    }
    __syncthreads();
    {
        int wv = tid >> 6;                       // wave in block: 0..7
        int lane = tid & 63;
        int wglobal = blockIdx.x * 8 + wv;       // 0..2047
#pragma unroll
        for (int q = 0; q < 2; ++q) {
            int word = wglobal * 2 + q;          // 0..4095
            int i = word >> 3, jw = word & 7;
            int j = jw * 64 + lane;
            float ix1 = sx1[i], iy1 = sy1[i], ix2 = sx2[i], iy2 = sy2[i];
            float ai = fmaxf(ix2 - ix1, 0.f) * fmaxf(iy2 - iy1, 0.f);
            float jx1 = sx1[j], jy1 = sy1[j], jx2 = sx2[j], jy2 = sy2[j];
            float aj = fmaxf(jx2 - jx1, 0.f) * fmaxf(jy2 - jy1, 0.f);
            float xx1 = fmaxf(ix1, jx1), yy1 = fmaxf(iy1, jy1);
            float xx2 = fminf(ix2, jx2), yy2 = fminf(iy2, jy2);
            float inter = fmaxf(xx2 - xx1, 0.f) * fmaxf(yy2 - yy1, 0.f);
            float iou = inter / (((ai + aj) - inter) + 1e-9f);
            bool bit = (j > i) && (iou > 0.3f);
            unsigned long long m = __ballot(bit);
            if (lane == 0) smaskG[word] = m;
        }
    }
    gg.sync();

    // ======== P5: block 0 — serial greedy sweep + masked output ========
    if (blockIdx.x == 0) {
        for (int p = tid; p < TOPK * 8; p += BLK) smask[p] = smaskG[p];
        bool validt = cand[tid * 7] > 0.5f;
        unsigned long long bal = __ballot(validt);
        if ((tid & 63) == 0) live[tid >> 6] = bal;
        __syncthreads();
        if (tid < 64) {
            int lane = tid;
            int lw = lane & 7;
            unsigned long long r = 0ull;
#pragma unroll
            for (int w = 0; w < 8; ++w) {
                unsigned long long lvw = live[w];
#pragma unroll 8
                for (int b2 = 0; b2 < 64; ++b2) {
                    int i = w * 64 + b2;
                    unsigned long long rowv = smask[i * 8 + lw];
                    unsigned rlo = (unsigned)__builtin_amdgcn_readlane((int)(unsigned)(r & 0xFFFFFFFFull), w);
                    unsigned rhi = (unsigned)__builtin_amdgcn_readlane((int)(unsigned)(r >> 32), w);
                    unsigned long long rw = (((unsigned long long)rhi) << 32) | (unsigned long long)rlo;
                    bool acc = (((lvw >> b2) & 1ull) != 0ull) && (((rw >> b2) & 1ull) == 0ull);
                    if (acc) r |= rowv;
                }
            }
            if (lane < 8) keepw[lane] = live[lane] & ~r;
        }
        __syncthreads();
        for (int p = tid; p < TOPK * 7; p += BLK) {
            int i = p / 7;
            unsigned long long kb = (keepw[i >> 6] >> (i & 63)) & 1ull;
            out[p] = kb ? cand[p] : 0.0f;
        }
    }
}

// ---------------- launch ----------------
extern "C" void kernel_launch(void* const* d_in, const int* in_sizes, int n_in,
                              void* d_out, int out_size, void* d_ws, size_t ws_size,
                              hipStream_t stream) {
    const float* p13 = (const float*)d_in[0];
    const float* p26 = (const float*)d_in[1];
    const float* p52 = (const float*)d_in[2];
    float* out = (float*)d_out;
    char* ws = (char*)d_ws;

    unsigned* hist             = (unsigned*)(ws + 0);                 // 2048 u32
    unsigned* cnt              = (unsigned*)(ws + 8192);              // 1 u32
    unsigned long long* keys   = (unsigned long long*)(ws + 8704);    // 2048 u64
    float* cand                = (float*)(ws + 25088);                // 512*7 f32
    unsigned long long* smaskG = (unsigned long long*)(ws + 39936);   // 4096 u64

    hipMemsetAsync(ws, 0, 8196, stream);   // zero hist + cnt

    void* args[] = { (void*)&p13, (void*)&p26, (void*)&p52, (void*)&hist, (void*)&cnt,
                     (void*)&keys, (void*)&cand, (void*)&smaskG, (void*)&out };
    hipLaunchCooperativeKernel((void*)k_all, dim3(GRID), dim3(BLK), args, 0, stream);
}

// Round 5
// 281.611 us; speedup vs baseline: 1.7410x; 1.1572x over previous
//
#include <hip/hip_runtime.h>

// ---------------- problem constants ----------------
#define N13E 16224      // 32*3*169
#define N26E 64896      // 32*3*676
#define NTOT 340704
#define BASE26 16224
#define BASE52 81120
#define KMAX 2048
#define TOPK 512

__device__ __forceinline__ float sigm(float x) { return 1.0f / (1.0f + expf(-x)); }

__device__ __forceinline__ unsigned long long pack_key(float v, int c) {
    unsigned u = __float_as_uint(v);
    unsigned ov = (u & 0x80000000u) ? ~u : (u | 0x80000000u);
    return (((unsigned long long)ov) << 32) | (unsigned long long)(unsigned)(127 - c);
}

// ================= K1: histogram of conf bits (R3-validated) =================
template <int HW>
__device__ __forceinline__ float load_logit(const float* __restrict__ p, int local) {
    int ba = local / HW;           // b*3 + a
    int hw = local - ba * HW;
    int b = ba / 3;
    int a = ba - b * 3;
    return p[(b * 255 + a * 85 + 4) * HW + hw];
}

__global__ void __launch_bounds__(256) k_hist(const float* __restrict__ p13,
                                              const float* __restrict__ p26,
                                              const float* __restrict__ p52,
                                              unsigned* __restrict__ hist) {
    int t = blockIdx.x * 256 + threadIdx.x;
    if (t >= NTOT) return;
    float logit;
    if (t < N13E)               logit = load_logit<169>(p13, t);
    else if (t < N13E + N26E)   logit = load_logit<676>(p26, t - N13E);
    else                        logit = load_logit<2704>(p52, t - (N13E + N26E));
    float conf = sigm(logit);
    if (conf > 0.5f) {
        unsigned bin = (__float_as_uint(conf) >> 12) - 0x3F000u;
        bin = (bin > 2047u) ? 2047u : bin;
        atomicAdd(&hist[bin], 1u);
    }
}

// ================= K2: per-block threshold scan + compact (R3-validated) =================
template <int HW, int BASE>
__device__ __forceinline__ void compact_one(const float* __restrict__ p, int local, unsigned thrv,
                                            unsigned* __restrict__ cnt,
                                            unsigned long long* __restrict__ keys) {
    int ba = local / HW;
    int hw = local - ba * HW;
    int b = ba / 3;
    int a = ba - b * 3;
    float logit = p[(b * 255 + a * 85 + 4) * HW + hw];
    float conf = sigm(logit);
    unsigned bits = __float_as_uint(conf);
    if (conf > 0.5f && bits >= thrv) {
        unsigned pos = atomicAdd(cnt, 1u);
        if (pos < (unsigned)KMAX) {
            unsigned concat = (unsigned)(BASE + (b * HW + hw) * 3 + a);
            keys[pos] = (((unsigned long long)bits) << 32) | (unsigned long long)(0xFFFFFFFFu - concat);
        }
    }
}

__global__ void __launch_bounds__(512) k_compact_scan(const float* __restrict__ p13,
                                                      const float* __restrict__ p26,
                                                      const float* __restrict__ p52,
                                                      const unsigned* __restrict__ hist,
                                                      unsigned* __restrict__ cnt,
                                                      unsigned long long* __restrict__ keys) {
    __shared__ unsigned tot[512];
    __shared__ unsigned thrS;
    int tid = threadIdx.x;

    unsigned loc[4]; unsigned s = 0u;
#pragma unroll
    for (int k = 0; k < 4; ++k) { loc[k] = hist[2047 - (tid * 4 + k)]; s += loc[k]; }
    tot[tid] = s;
    __syncthreads();
    for (int off = 1; off < 512; off <<= 1) {
        unsigned u = (tid >= off) ? tot[tid - off] : 0u;
        __syncthreads();
        tot[tid] += u;
        __syncthreads();
    }
    unsigned excl = tot[tid] - s;
    unsigned total = tot[511];
    if (total < (unsigned)TOPK) {
        if (tid == 0) thrS = 0x3F000001u;     // accept every conf > 0.5
    } else {
        unsigned run = excl;
#pragma unroll
        for (int k = 0; k < 4; ++k) {
            unsigned c = run + loc[k];
            if (run < (unsigned)TOPK && c >= (unsigned)TOPK) {  // unique crossing
                int bin = 2047 - (tid * 4 + k);
                thrS = ((unsigned)(bin + 0x3F000)) << 12;
            }
            run = c;
        }
    }
    __syncthreads();
    unsigned thrv = thrS;

    int t = blockIdx.x * 512 + tid;
    if (t >= NTOT) return;
    if (t < N13E)               compact_one<169, 0>(p13, t, thrv, cnt, keys);
    else if (t < N13E + N26E)   compact_one<676, BASE26>(p26, t - N13E, thrv, cnt, keys);
    else                        compact_one<2704, BASE52>(p52, t - (N13E + N26E), thrv, cnt, keys);
}

// ================= K3: rank-select (64 blocks, unrolled) + decode (R4-P3-validated) =================
template <int HW, int W>
__device__ __forceinline__ void decode64(const float* __restrict__ p, int local, float strideF,
                                         float aw0, float ah0, float aw1, float ah1, float aw2, float ah2,
                                         float conf, float* __restrict__ outrow, int lane) {
    int a = local % 3;
    int cell = local / 3;
    int b = cell / HW;
    int hw = cell - b * HW;
    int h = hw / W;
    int wc = hw - h * W;
    int cb = b * 255 + a * 85;
    float v1 = p[(cb + 5 + lane) * HW + hw];
    unsigned long long k1 = pack_key(v1, lane);
    if (lane < 16) {
        float v2 = p[(cb + 69 + lane) * HW + hw];   // classes 64..79
        unsigned long long k2 = pack_key(v2, lane + 64);
        if (k2 > k1) k1 = k2;
    }
#pragma unroll
    for (int m = 32; m >= 1; m >>= 1) {
        unsigned long long o = __shfl_xor(k1, m, 64);
        if (o > k1) k1 = o;
    }
    if (lane == 0) {
        int cls = 127 - (int)(unsigned)(k1 & 0xFFFFFFFFull);
        float t0 = p[(cb + 0) * HW + hw];
        float t1 = p[(cb + 1) * HW + hw];
        float t2 = p[(cb + 2) * HW + hw];
        float t3 = p[(cb + 3) * HW + hw];
        float aw = (a == 0) ? aw0 : ((a == 1) ? aw1 : aw2);
        float ah = (a == 0) ? ah0 : ((a == 1) ? ah1 : ah2);
        float sx = sigm(t0);
        float sy = sigm(t1);
        float bw = aw * expf(t2);
        float bh = ah * expf(t3);
        float cx = ((float)wc + sx) * strideF;
        float cy = ((float)h + sy) * strideF;
        float w0 = bw * 0.5f, h0 = bh * 0.5f;
        outrow[0] = conf;
        outrow[1] = cx - w0;
        outrow[2] = cy - h0;
        outrow[3] = cx + w0;
        outrow[4] = cy + h0;
        outrow[5] = (float)cls;
        outrow[6] = (float)b;
    }
}

__global__ void __launch_bounds__(512) k_rank_decode(const float* __restrict__ p13,
                                                     const float* __restrict__ p26,
                                                     const float* __restrict__ p52,
                                                     const unsigned* __restrict__ cnt,
                                                     const unsigned long long* __restrict__ keys,
                                                     float* __restrict__ cand) {
    __shared__ unsigned long long keysL[KMAX];     // 16 KB
    __shared__ unsigned long long sortedL[8];
    int tid = threadIdx.x;

    unsigned n = *cnt; if (n > (unsigned)KMAX) n = (unsigned)KMAX;
    int npad = ((int)n + 7) & ~7;
    for (int j = tid; j < npad; j += 512) keysL[j] = (j < (int)n) ? keys[j] : 0ull;
    if (tid < 8) sortedL[tid] = 0ull;
    __syncthreads();
    int lo = blockIdx.x * 8;                      // rank range [lo, lo+8)
    unsigned long long mine[4]; unsigned rk[4]; int nown = 0;
#pragma unroll
    for (int k = 0; k < 4; ++k) {
        int idx = tid + k * 512;
        if (idx < (int)n) { mine[nown] = keysL[idx]; rk[nown] = 0u; ++nown; }
    }
    for (int j = 0; j < npad; j += 8) {           // 8-wide unroll: independent LDS loads
        unsigned long long kk[8];
#pragma unroll
        for (int u = 0; u < 8; ++u) kk[u] = keysL[j + u];
        for (int m = 0; m < nown; ++m) {
            unsigned acc = 0u;
#pragma unroll
            for (int u = 0; u < 8; ++u) acc += (kk[u] > mine[m]) ? 1u : 0u;
            rk[m] += acc;
        }
    }
    for (int m = 0; m < nown; ++m) {
        unsigned r = rk[m];
        if (r >= (unsigned)lo && r < (unsigned)(lo + 8)) sortedL[r - lo] = mine[m];
    }
    __syncthreads();

    // decode: 8 boxes per block, 64 lanes per box
    int bb = tid >> 6;
    int lane = tid & 63;
    int box = lo + bb;
    unsigned long long key = sortedL[bb];
    unsigned sb = (unsigned)(key >> 32);
    float* row = cand + box * 7;
    if (sb == 0u) {
        if (lane < 7) row[lane] = 0.0f;
        return;
    }
    unsigned idx = 0xFFFFFFFFu - (unsigned)(key & 0xFFFFFFFFull);
    float conf = __uint_as_float(sb);
    if (idx < N13E)
        decode64<169, 13>(p13, (int)idx, 32.0f, 116.f, 90.f, 156.f, 198.f, 373.f, 326.f, conf, row, lane);
    else if (idx < N13E + N26E)
        decode64<676, 26>(p26, (int)idx - BASE26, 16.0f, 30.f, 61.f, 62.f, 45.f, 59.f, 119.f, conf, row, lane);
    else
        decode64<2704, 52>(p52, (int)idx - BASE52, 8.0f, 10.f, 13.f, 16.f, 30.f, 33.f, 23.f, conf, row, lane);
}

// ================= K4: mask + serial greedy NMS + masked output (R3-validated) =================
__global__ void __launch_bounds__(512) k_nms(const float* __restrict__ cand,
                                             float* __restrict__ out) {
    __shared__ float cx1[TOPK], cy1[TOPK], cx2[TOPK], cy2[TOPK], car[TOPK], cco[TOPK];
    __shared__ unsigned long long smask[TOPK * 8];   // 32 KB
    __shared__ unsigned long long live[8], keepw[8];
    int tid = threadIdx.x;

    {
        int p = tid;              // 512 threads, 512 boxes
        float c0 = cand[p * 7 + 0];
        float x1 = cand[p * 7 + 1], y1 = cand[p * 7 + 2];
        float x2 = cand[p * 7 + 3], y2 = cand[p * 7 + 4];
        cco[p] = c0; cx1[p] = x1; cy1[p] = y1; cx2[p] = x2; cy2[p] = y2;
        car[p] = fmaxf(x2 - x1, 0.f) * fmaxf(y2 - y1, 0.f);
    }
    __syncthreads();

    {
        int i = tid;
        float x1 = cx1[i], y1 = cy1[i], x2 = cx2[i], y2 = cy2[i];
        float ai = car[i];
#pragma unroll
        for (int jw = 0; jw < 8; ++jw) {
            unsigned long long m = 0ull;
            int j0 = jw * 64;
            if (i < j0 + 63) {    // word has at least one j > i
                for (int bj = 0; bj < 64; ++bj) {
                    int j = j0 + bj;
                    float jx1 = cx1[j], jy1 = cy1[j], jx2 = cx2[j], jy2 = cy2[j];
                    float aj = car[j];
                    float xx1 = fmaxf(x1, jx1), yy1 = fmaxf(y1, jy1);
                    float xx2 = fminf(x2, jx2), yy2 = fminf(y2, jy2);
                    float inter = fmaxf(xx2 - xx1, 0.f) * fmaxf(yy2 - yy1, 0.f);
                    float iou = inter / (((ai + aj) - inter) + 1e-9f);
                    if ((j > i) && (iou > 0.3f)) m |= (1ull << bj);
                }
            }
            smask[i * 8 + jw] = m;
        }
    }
    bool validt = cco[tid] > 0.5f;
    unsigned long long bal = __ballot(validt);
    if ((tid & 63) == 0) live[tid >> 6] = bal;
    __syncthreads();

    if (tid < 64) {
        int lane = tid;
        int lw = lane & 7;
        unsigned long long r = 0ull;
#pragma unroll
        for (int w = 0; w < 8; ++w) {
            unsigned long long lvw = live[w];
#pragma unroll 8
            for (int b2 = 0; b2 < 64; ++b2) {
                int i = w * 64 + b2;
                unsigned long long rowv = smask[i * 8 + lw];
                unsigned rlo = (unsigned)__builtin_amdgcn_readlane((int)(unsigned)(r & 0xFFFFFFFFull), w);
                unsigned rhi = (unsigned)__builtin_amdgcn_readlane((int)(unsigned)(r >> 32), w);
                unsigned long long rw = (((unsigned long long)rhi) << 32) | (unsigned long long)rlo;
                bool acc = (((lvw >> b2) & 1ull) != 0ull) && (((rw >> b2) & 1ull) == 0ull);
                if (acc) r |= rowv;
            }
        }
        if (lane < 8) keepw[lane] = live[lane] & ~r;
    }
    __syncthreads();

    for (int p = tid; p < TOPK * 7; p += 512) {
        int i = p / 7;
        unsigned long long kb = (keepw[i >> 6] >> (i & 63)) & 1ull;
        out[p] = kb ? cand[p] : 0.0f;
    }
}

// ---------------- launch ----------------
extern "C" void kernel_launch(void* const* d_in, const int* in_sizes, int n_in,
                              void* d_out, int out_size, void* d_ws, size_t ws_size,
                              hipStream_t stream) {
    const float* p13 = (const float*)d_in[0];
    const float* p26 = (const float*)d_in[1];
    const float* p52 = (const float*)d_in[2];
    float* out = (float*)d_out;
    char* ws = (char*)d_ws;

    unsigned* hist           = (unsigned*)(ws + 0);                // 2048 u32
    unsigned* cnt            = (unsigned*)(ws + 8192);             // 1 u32
    unsigned long long* keys = (unsigned long long*)(ws + 8704);   // 2048 u64
    float* cand              = (float*)(ws + 25088);               // 512*7 f32

    hipMemsetAsync(ws, 0, 8196, stream);   // zero hist + cnt

    int gh = (NTOT + 255) / 256;   // 1331
    int gc = (NTOT + 511) / 512;   // 666
    k_hist<<<gh, 256, 0, stream>>>(p13, p26, p52, hist);
    k_compact_scan<<<gc, 512, 0, stream>>>(p13, p26, p52, hist, cnt, keys);
    k_rank_decode<<<64, 512, 0, stream>>>(p13, p26, p52, cnt, keys, cand);
    k_nms<<<1, 512, 0, stream>>>(cand, out);
}

// Round 6
// 234.048 us; speedup vs baseline: 2.0948x; 1.2032x over previous
//
#include <hip/hip_runtime.h>

// ---------------- problem constants ----------------
#define N13E 16224      // 32*3*169
#define N26E 64896      // 32*3*676
#define NTOT 340704
#define BASE26 16224
#define BASE52 81120
#define KMAX 2048
#define TOPK 512

__device__ __forceinline__ float sigm(float x) { return 1.0f / (1.0f + expf(-x)); }

__device__ __forceinline__ unsigned long long pack_key(float v, int c) {
    unsigned u = __float_as_uint(v);
    unsigned ov = (u & 0x80000000u) ? ~u : (u | 0x80000000u);
    return (((unsigned long long)ov) << 32) | (unsigned long long)(unsigned)(127 - c);
}

// ================= K1: histogram of conf bits (R3-validated) =================
template <int HW>
__device__ __forceinline__ float load_logit(const float* __restrict__ p, int local) {
    int ba = local / HW;           // b*3 + a
    int hw = local - ba * HW;
    int b = ba / 3;
    int a = ba - b * 3;
    return p[(b * 255 + a * 85 + 4) * HW + hw];
}

__global__ void __launch_bounds__(256) k_hist(const float* __restrict__ p13,
                                              const float* __restrict__ p26,
                                              const float* __restrict__ p52,
                                              unsigned* __restrict__ hist) {
    int t = blockIdx.x * 256 + threadIdx.x;
    if (t >= NTOT) return;
    float logit;
    if (t < N13E)               logit = load_logit<169>(p13, t);
    else if (t < N13E + N26E)   logit = load_logit<676>(p26, t - N13E);
    else                        logit = load_logit<2704>(p52, t - (N13E + N26E));
    float conf = sigm(logit);
    if (conf > 0.5f) {
        unsigned bin = (__float_as_uint(conf) >> 12) - 0x3F000u;
        bin = (bin > 2047u) ? 2047u : bin;
        atomicAdd(&hist[bin], 1u);
    }
}

// ================= K2: per-block threshold scan + compact (R3-validated) =================
template <int HW, int BASE>
__device__ __forceinline__ void compact_one(const float* __restrict__ p, int local, unsigned thrv,
                                            unsigned* __restrict__ cnt,
                                            unsigned long long* __restrict__ keys) {
    int ba = local / HW;
    int hw = local - ba * HW;
    int b = ba / 3;
    int a = ba - b * 3;
    float logit = p[(b * 255 + a * 85 + 4) * HW + hw];
    float conf = sigm(logit);
    unsigned bits = __float_as_uint(conf);
    if (conf > 0.5f && bits >= thrv) {
        unsigned pos = atomicAdd(cnt, 1u);
        if (pos < (unsigned)KMAX) {
            unsigned concat = (unsigned)(BASE + (b * HW + hw) * 3 + a);
            keys[pos] = (((unsigned long long)bits) << 32) | (unsigned long long)(0xFFFFFFFFu - concat);
        }
    }
}

__global__ void __launch_bounds__(512) k_compact_scan(const float* __restrict__ p13,
                                                      const float* __restrict__ p26,
                                                      const float* __restrict__ p52,
                                                      const unsigned* __restrict__ hist,
                                                      unsigned* __restrict__ cnt,
                                                      unsigned long long* __restrict__ keys) {
    __shared__ unsigned tot[512];
    __shared__ unsigned thrS;
    int tid = threadIdx.x;

    unsigned loc[4]; unsigned s = 0u;
#pragma unroll
    for (int k = 0; k < 4; ++k) { loc[k] = hist[2047 - (tid * 4 + k)]; s += loc[k]; }
    tot[tid] = s;
    __syncthreads();
    for (int off = 1; off < 512; off <<= 1) {
        unsigned u = (tid >= off) ? tot[tid - off] : 0u;
        __syncthreads();
        tot[tid] += u;
        __syncthreads();
    }
    unsigned excl = tot[tid] - s;
    unsigned total = tot[511];
    if (total < (unsigned)TOPK) {
        if (tid == 0) thrS = 0x3F000001u;     // accept every conf > 0.5
    } else {
        unsigned run = excl;
#pragma unroll
        for (int k = 0; k < 4; ++k) {
            unsigned c = run + loc[k];
            if (run < (unsigned)TOPK && c >= (unsigned)TOPK) {  // unique crossing
                int bin = 2047 - (tid * 4 + k);
                thrS = ((unsigned)(bin + 0x3F000)) << 12;
            }
            run = c;
        }
    }
    __syncthreads();
    unsigned thrv = thrS;

    int t = blockIdx.x * 512 + tid;
    if (t >= NTOT) return;
    if (t < N13E)               compact_one<169, 0>(p13, t, thrv, cnt, keys);
    else if (t < N13E + N26E)   compact_one<676, BASE26>(p26, t - N13E, thrv, cnt, keys);
    else                        compact_one<2704, BASE52>(p52, t - (N13E + N26E), thrv, cnt, keys);
}

// ================= K3: rank-select (64 blocks, unrolled) + decode (R4/R5-validated) =================
template <int HW, int W>
__device__ __forceinline__ void decode64(const float* __restrict__ p, int local, float strideF,
                                         float aw0, float ah0, float aw1, float ah1, float aw2, float ah2,
                                         float conf, float* __restrict__ outrow, int lane) {
    int a = local % 3;
    int cell = local / 3;
    int b = cell / HW;
    int hw = cell - b * HW;
    int h = hw / W;
    int wc = hw - h * W;
    int cb = b * 255 + a * 85;
    float v1 = p[(cb + 5 + lane) * HW + hw];
    unsigned long long k1 = pack_key(v1, lane);
    if (lane < 16) {
        float v2 = p[(cb + 69 + lane) * HW + hw];   // classes 64..79
        unsigned long long k2 = pack_key(v2, lane + 64);
        if (k2 > k1) k1 = k2;
    }
#pragma unroll
    for (int m = 32; m >= 1; m >>= 1) {
        unsigned long long o = __shfl_xor(k1, m, 64);
        if (o > k1) k1 = o;
    }
    if (lane == 0) {
        int cls = 127 - (int)(unsigned)(k1 & 0xFFFFFFFFull);
        float t0 = p[(cb + 0) * HW + hw];
        float t1 = p[(cb + 1) * HW + hw];
        float t2 = p[(cb + 2) * HW + hw];
        float t3 = p[(cb + 3) * HW + hw];
        float aw = (a == 0) ? aw0 : ((a == 1) ? aw1 : aw2);
        float ah = (a == 0) ? ah0 : ((a == 1) ? ah1 : ah2);
        float sx = sigm(t0);
        float sy = sigm(t1);
        float bw = aw * expf(t2);
        float bh = ah * expf(t3);
        float cx = ((float)wc + sx) * strideF;
        float cy = ((float)h + sy) * strideF;
        float w0 = bw * 0.5f, h0 = bh * 0.5f;
        outrow[0] = conf;
        outrow[1] = cx - w0;
        outrow[2] = cy - h0;
        outrow[3] = cx + w0;
        outrow[4] = cy + h0;
        outrow[5] = (float)cls;
        outrow[6] = (float)b;
    }
}

__global__ void __launch_bounds__(512) k_rank_decode(const float* __restrict__ p13,
                                                     const float* __restrict__ p26,
                                                     const float* __restrict__ p52,
                                                     const unsigned* __restrict__ cnt,
                                                     const unsigned long long* __restrict__ keys,
                                                     float* __restrict__ cand) {
    __shared__ unsigned long long keysL[KMAX];     // 16 KB
    __shared__ unsigned long long sortedL[8];
    int tid = threadIdx.x;

    unsigned n = *cnt; if (n > (unsigned)KMAX) n = (unsigned)KMAX;
    int npad = ((int)n + 7) & ~7;
    for (int j = tid; j < npad; j += 512) keysL[j] = (j < (int)n) ? keys[j] : 0ull;
    if (tid < 8) sortedL[tid] = 0ull;
    __syncthreads();
    int lo = blockIdx.x * 8;                      // rank range [lo, lo+8)
    unsigned long long mine[4]; unsigned rk[4]; int nown = 0;
#pragma unroll
    for (int k = 0; k < 4; ++k) {
        int idx = tid + k * 512;
        if (idx < (int)n) { mine[nown] = keysL[idx]; rk[nown] = 0u; ++nown; }
    }
    for (int j = 0; j < npad; j += 8) {           // 8-wide unroll: independent LDS loads
        unsigned long long kk[8];
#pragma unroll
        for (int u = 0; u < 8; ++u) kk[u] = keysL[j + u];
        for (int m = 0; m < nown; ++m) {
            unsigned acc = 0u;
#pragma unroll
            for (int u = 0; u < 8; ++u) acc += (kk[u] > mine[m]) ? 1u : 0u;
            rk[m] += acc;
        }
    }
    for (int m = 0; m < nown; ++m) {
        unsigned r = rk[m];
        if (r >= (unsigned)lo && r < (unsigned)(lo + 8)) sortedL[r - lo] = mine[m];
    }
    __syncthreads();

    // decode: 8 boxes per block, 64 lanes per box
    int bb = tid >> 6;
    int lane = tid & 63;
    int box = lo + bb;
    unsigned long long key = sortedL[bb];
    unsigned sb = (unsigned)(key >> 32);
    float* row = cand + box * 7;
    if (sb == 0u) {
        if (lane < 7) row[lane] = 0.0f;
        return;
    }
    unsigned idx = 0xFFFFFFFFu - (unsigned)(key & 0xFFFFFFFFull);
    float conf = __uint_as_float(sb);
    if (idx < N13E)
        decode64<169, 13>(p13, (int)idx, 32.0f, 116.f, 90.f, 156.f, 198.f, 373.f, 326.f, conf, row, lane);
    else if (idx < N13E + N26E)
        decode64<676, 26>(p26, (int)idx - BASE26, 16.0f, 30.f, 61.f, 62.f, 45.f, 59.f, 119.f, conf, row, lane);
    else
        decode64<2704, 52>(p52, (int)idx - BASE52, 8.0f, 10.f, 13.f, 16.f, 30.f, 33.f, 23.f, conf, row, lane);
}

// ================= K4: suppression mask, ballot, 32 blocks (R4-P4-validated form) =================
__global__ void __launch_bounds__(512) k_mask(const float* __restrict__ cand,
                                              unsigned long long* __restrict__ smaskG) {
    __shared__ float sx1[TOPK], sy1[TOPK], sx2[TOPK], sy2[TOPK];  // 8 KB
    int tid = threadIdx.x;
    for (int p = tid; p < TOPK; p += 512) {
        const float* r = cand + p * 7;
        sx1[p] = r[1]; sy1[p] = r[2]; sx2[p] = r[3]; sy2[p] = r[4];
    }
    __syncthreads();
    int wv = tid >> 6;                        // wave in block: 0..7
    int lane = tid & 63;
    int gwave = blockIdx.x * 8 + wv;          // 0..255
#pragma unroll
    for (int q = 0; q < 16; ++q) {
        int word = gwave * 16 + q;            // 0..4095
        int i = word >> 3, jw = word & 7;
        int j = jw * 64 + lane;
        float ix1 = sx1[i], iy1 = sy1[i], ix2 = sx2[i], iy2 = sy2[i];
        float ai = fmaxf(ix2 - ix1, 0.f) * fmaxf(iy2 - iy1, 0.f);
        float jx1 = sx1[j], jy1 = sy1[j], jx2 = sx2[j], jy2 = sy2[j];
        float aj = fmaxf(jx2 - jx1, 0.f) * fmaxf(jy2 - jy1, 0.f);
        float xx1 = fmaxf(ix1, jx1), yy1 = fmaxf(iy1, jy1);
        float xx2 = fminf(ix2, jx2), yy2 = fminf(iy2, jy2);
        float inter = fmaxf(xx2 - xx1, 0.f) * fmaxf(yy2 - yy1, 0.f);
        float iou = inter / (((ai + aj) - inter) + 1e-9f);
        bool bit = (j > i) && (iou > 0.3f);
        unsigned long long m = __ballot(bit);
        if (lane == 0) smaskG[word] = m;
    }
}

// ================= K5: serial greedy sweep + masked output, 1 block (R4-P5-validated) =================
__global__ void __launch_bounds__(512) k_sweep(const float* __restrict__ cand,
                                               const unsigned long long* __restrict__ smaskG,
                                               float* __restrict__ out) {
    __shared__ unsigned long long smask[TOPK * 8];   // 32 KB
    __shared__ unsigned long long live[8], keepw[8];
    int tid = threadIdx.x;
    for (int p = tid; p < TOPK * 8; p += 512) smask[p] = smaskG[p];
    bool validt = cand[tid * 7] > 0.5f;
    unsigned long long bal = __ballot(validt);
    if ((tid & 63) == 0) live[tid >> 6] = bal;
    __syncthreads();
    if (tid < 64) {
        int lane = tid;
        int lw = lane & 7;
        unsigned long long r = 0ull;
#pragma unroll
        for (int w = 0; w < 8; ++w) {
            unsigned long long lvw = live[w];
#pragma unroll 8
            for (int b2 = 0; b2 < 64; ++b2) {
                int i = w * 64 + b2;
                unsigned long long rowv = smask[i * 8 + lw];
                unsigned rlo = (unsigned)__builtin_amdgcn_readlane((int)(unsigned)(r & 0xFFFFFFFFull), w);
                unsigned rhi = (unsigned)__builtin_amdgcn_readlane((int)(unsigned)(r >> 32), w);
                unsigned long long rw = (((unsigned long long)rhi) << 32) | (unsigned long long)rlo;
                bool acc = (((lvw >> b2) & 1ull) != 0ull) && (((rw >> b2) & 1ull) == 0ull);
                if (acc) r |= rowv;
            }
        }
        if (lane < 8) keepw[lane] = live[lane] & ~r;
    }
    __syncthreads();
    for (int p = tid; p < TOPK * 7; p += 512) {
        int i = p / 7;
        unsigned long long kb = (keepw[i >> 6] >> (i & 63)) & 1ull;
        out[p] = kb ? cand[p] : 0.0f;
    }
}

// ---------------- launch ----------------
extern "C" void kernel_launch(void* const* d_in, const int* in_sizes, int n_in,
                              void* d_out, int out_size, void* d_ws, size_t ws_size,
                              hipStream_t stream) {
    const float* p13 = (const float*)d_in[0];
    const float* p26 = (const float*)d_in[1];
    const float* p52 = (const float*)d_in[2];
    float* out = (float*)d_out;
    char* ws = (char*)d_ws;

    unsigned* hist             = (unsigned*)(ws + 0);                // 2048 u32
    unsigned* cnt              = (unsigned*)(ws + 8192);             // 1 u32
    unsigned long long* keys   = (unsigned long long*)(ws + 8704);   // 2048 u64
    float* cand                = (float*)(ws + 25088);               // 512*7 f32
    unsigned long long* smaskG = (unsigned long long*)(ws + 39936);  // 4096 u64

    hipMemsetAsync(ws, 0, 8196, stream);   // zero hist + cnt

    int gh = (NTOT + 255) / 256;   // 1331
    int gc = (NTOT + 511) / 512;   // 666
    k_hist<<<gh, 256, 0, stream>>>(p13, p26, p52, hist);
    k_compact_scan<<<gc, 512, 0, stream>>>(p13, p26, p52, hist, cnt, keys);
    k_rank_decode<<<64, 512, 0, stream>>>(p13, p26, p52, cnt, keys, cand);
    k_mask<<<32, 512, 0, stream>>>(cand, smaskG);
    k_sweep<<<1, 512, 0, stream>>>(cand, smaskG, out);
}